// Round 3
// baseline (875.385 us; speedup 1.0000x reference)
//
#include <hip/hip_runtime.h>
#include <cstdint>
#include <cstddef>

typedef __bf16 bf16;
typedef __bf16 bf16x8 __attribute__((ext_vector_type(8)));
typedef __bf16 bf16v4 __attribute__((ext_vector_type(4)));
typedef float  f32x4  __attribute__((ext_vector_type(4)));

// Problem constants: B=128, N=49, G=4096, H=1024, A=1024
#define PB   128
#define PN   49
#define PG   4096
#define PH   1024
#define PA   1024
#define PM1  (PB * PN)   // 6272

// ---------------------------------------------------------------------------
// Detect input dtype on-device. fp32 data viewed as bf16 words: even words are
// mantissa garbage (log-uniform magnitude); true bf16 data is ~N(0,1).
// flag = 1 -> inputs are bf16;  flag = 0 -> inputs are fp32.
// ---------------------------------------------------------------------------
__global__ __launch_bounds__(256) void detect_kernel(
    const unsigned short* __restrict__ raw, int* __restrict__ flag)
{
    __shared__ int cnt;
    if (threadIdx.x == 0) cnt = 0;
    __syncthreads();
    unsigned short u = raw[threadIdx.x];
    float x = __uint_as_float(((unsigned int)u) << 16);
    float a = fabsf(x);
    atomicAdd(&cnt, (a >= 1e-7f && a <= 128.f) ? 1 : 0);
    __syncthreads();
    if (threadIdx.x == 0) flag[0] = (cnt >= 200) ? 1 : 0;
}

__device__ __forceinline__ float ldin(const void* p, size_t i, bool in32) {
    return in32 ? ((const float*)p)[i] : (float)((const bf16*)p)[i];
}

// ---------------------------------------------------------------------------
// GEMM: C[M,N] = A[M,K] @ Bt[N,K]^T.  128x128 tile, BK=64, 4 waves (2x2 of
// 64x64), mfma 16x16x32 bf16.  VGPR-staged LDS with (chunk+row)&7 rotation
// (write and read use the SAME formula -> trivially consistent; spreads
// ds_read_b128 over all 8 bank-groups, 2 lanes/bank = free per m136).
// A/Bt may be raw inputs (xAdapt=1: dtype from flag) or canonical bf16.
// BF16OUT=1: write bf16 to Cb.  Else fp32 to Cf + blockIdx.z*M*N (split-K).
// ---------------------------------------------------------------------------
template <int BF16OUT>
__global__ __launch_bounds__(256, 2) void gemm_kernel(
    const void* __restrict__ Araw, const void* __restrict__ Btraw,
    const int* __restrict__ flag, int aAdapt, int bAdapt,
    float* __restrict__ Cf, bf16* __restrict__ Cb,
    int M, int N, int K, int kTilesPerSplit)
{
    __shared__ __align__(16) bf16 lds[2 * 128 * 64];
    bf16* As = lds;
    bf16* Bs = lds + 128 * 64;

    const bool a32 = aAdapt && (flag[0] == 0);
    const bool b32 = bAdapt && (flag[0] == 0);

    const int tid  = threadIdx.x;
    const int m0   = blockIdx.y * 128;
    const int n0   = blockIdx.x * 128;
    const int kt0  = blockIdx.z * kTilesPerSplit;

    const int wave = tid >> 6;
    const int lane = tid & 63;
    const int wm   = (wave >> 1) * 64;
    const int wn   = (wave & 1) * 64;
    const int lm   = lane & 15;
    const int q    = lane >> 4;

    f32x4 acc[4][4];
#pragma unroll
    for (int i = 0; i < 4; ++i)
#pragma unroll
        for (int j = 0; j < 4; ++j) acc[i][j] = (f32x4)0.0f;

    for (int kt = 0; kt < kTilesPerSplit; ++kt) {
        const int k0 = (kt0 + kt) * 64;
#pragma unroll
        for (int it = 0; it < 4; ++it) {
            int p    = it * 256 + tid;
            int row  = p >> 3;
            int ch   = p & 7;
            int slot = row * 8 + ((ch + row) & 7);
            size_t offA = (size_t)(m0 + row) * K + k0 + ch * 8;
            size_t offB = (size_t)(n0 + row) * K + k0 + ch * 8;
            bf16x8 va, vb;
            if (a32) {
                const float* pf = (const float*)Araw + offA;
                f32x4 lo = *(const f32x4*)pf, hi = *(const f32x4*)(pf + 4);
#pragma unroll
                for (int j = 0; j < 4; ++j) { va[j] = (bf16)lo[j]; va[4 + j] = (bf16)hi[j]; }
            } else {
                va = *(const bf16x8*)((const bf16*)Araw + offA);
            }
            if (b32) {
                const float* pf = (const float*)Btraw + offB;
                f32x4 lo = *(const f32x4*)pf, hi = *(const f32x4*)(pf + 4);
#pragma unroll
                for (int j = 0; j < 4; ++j) { vb[j] = (bf16)lo[j]; vb[4 + j] = (bf16)hi[j]; }
            } else {
                vb = *(const bf16x8*)((const bf16*)Btraw + offB);
            }
            *(bf16x8*)(As + slot * 8) = va;
            *(bf16x8*)(Bs + slot * 8) = vb;
        }
        __syncthreads();

#pragma unroll
        for (int s = 0; s < 2; ++s) {
            bf16x8 af[4], bfr[4];
            const int c = s * 4 + q;
#pragma unroll
            for (int mi = 0; mi < 4; ++mi) {
                int row  = wm + mi * 16 + lm;
                int slot = row * 8 + ((c + row) & 7);
                af[mi] = *(const bf16x8*)(As + slot * 8);
            }
#pragma unroll
            for (int ni = 0; ni < 4; ++ni) {
                int row  = wn + ni * 16 + lm;
                int slot = row * 8 + ((c + row) & 7);
                bfr[ni] = *(const bf16x8*)(Bs + slot * 8);
            }
#pragma unroll
            for (int mi = 0; mi < 4; ++mi)
#pragma unroll
                for (int ni = 0; ni < 4; ++ni)
                    acc[mi][ni] = __builtin_amdgcn_mfma_f32_16x16x32_bf16(
                        af[mi], bfr[ni], acc[mi][ni], 0, 0, 0);
        }
        __syncthreads();
    }

#pragma unroll
    for (int mi = 0; mi < 4; ++mi)
#pragma unroll
        for (int ni = 0; ni < 4; ++ni)
#pragma unroll
            for (int r = 0; r < 4; ++r) {
                int row = m0 + wm + mi * 16 + q * 4 + r;
                int col = n0 + wn + ni * 16 + lm;
                if (BF16OUT) {
                    Cb[(size_t)row * N + col] = (bf16)acc[mi][ni][r];
                } else {
                    Cf[(size_t)blockIdx.z * M * N + (size_t)row * N + col] = acc[mi][ni][r];
                }
            }
}

// ---------------------------------------------------------------------------
// Adaptive transpose: raw [R,C] (bf16 or fp32 by flag) -> bf16 [C,R].
// grid (C/64, R/64)
// ---------------------------------------------------------------------------
__global__ __launch_bounds__(256) void transpose_kernel(
    const void* __restrict__ in, const int* __restrict__ flag,
    bf16* __restrict__ out, int R, int C)
{
    __shared__ bf16 tile[64][65];
    const bool in32 = (flag[0] == 0);
    const int r0 = blockIdx.y * 64, c0 = blockIdx.x * 64;
    const int tx = threadIdx.x & 15, ty = threadIdx.x >> 4;
#pragma unroll
    for (int it = 0; it < 4; ++it) {
        int r = it * 16 + ty;
        size_t base = (size_t)(r0 + r) * C + c0 + tx * 4;
        if (in32) {
            f32x4 v = *(const f32x4*)((const float*)in + base);
#pragma unroll
            for (int i = 0; i < 4; ++i) tile[r][tx * 4 + i] = (bf16)v[i];
        } else {
            bf16v4 v = *(const bf16v4*)((const bf16*)in + base);
#pragma unroll
            for (int i = 0; i < 4; ++i) tile[r][tx * 4 + i] = v[i];
        }
    }
    __syncthreads();
#pragma unroll
    for (int it = 0; it < 4; ++it) {
        int c = it * 16 + ty;
        bf16v4 v;
#pragma unroll
        for (int i = 0; i < 4; ++i) v[i] = tile[tx * 4 + i][c];
        *(bf16v4*)(out + (size_t)(c0 + c) * R + r0 + tx * 4) = v;
    }
}

// part[zy][c] = sum_{r in slice} x[r] * W[r,c]
// xMode 0: x is fp32 ws buffer; 1: x is a raw input (flag-adaptive)
__global__ __launch_bounds__(256) void matvec_part_kernel(
    const void* __restrict__ x, const void* __restrict__ W,
    const int* __restrict__ flag, int xMode,
    float* __restrict__ part, int C, int rPer)
{
    const bool in32 = (flag[0] == 0);
    int c  = blockIdx.x * 256 + threadIdx.x;
    int r0 = blockIdx.y * rPer;
    float acc = 0.f;
    for (int r = r0; r < r0 + rPer; ++r) {
        float xv = (xMode == 0) ? ((const float*)x)[r] : ldin(x, r, in32);
        acc += xv * ldin(W, (size_t)r * C + c, in32);
    }
    part[(size_t)blockIdx.y * C + c] = acc;
}

// y[c] = sum_s part[s][c] (+ addv[c] raw input, optional)
__global__ __launch_bounds__(256) void matvec_fin_kernel(
    const float* __restrict__ part, const void* __restrict__ addv,
    const int* __restrict__ flag, float* __restrict__ y, int S, int C)
{
    const bool in32 = (flag[0] == 0);
    int c = blockIdx.x * 256 + threadIdx.x;
    float acc = addv ? ldin(addv, c, in32) : 0.f;
    for (int s = 0; s < S; ++s) acc += part[(size_t)s * C + c];
    y[c] = acc;
}

__global__ __launch_bounds__(256) void reduce4_kernel(
    const float* __restrict__ parts, float* __restrict__ out, int MN)
{
    int i = blockIdx.x * 256 + threadIdx.x;
    out[i] = parts[i] + parts[i + MN] + parts[i + 2 * MN] + parts[i + 3 * MN];
}

// scores -> softmax -> alpha; one block per batch
__global__ __launch_bounds__(256) void attn_kernel(
    const bf16* __restrict__ t, const float* __restrict__ sproj,
    const float* __restrict__ tbias, const void* __restrict__ cov,
    const void* __restrict__ Wc, const void* __restrict__ v,
    const int* __restrict__ flag, float* __restrict__ alpha)
{
    const bool in32 = (flag[0] == 0);
    const int b = blockIdx.x, tid = threadIdx.x;
    __shared__ float red[4];
    __shared__ float sc[PN];

    float sp[4], vv[4], wc[4];
#pragma unroll
    for (int i = 0; i < 4; ++i) {
        int a = tid + i * 256;
        sp[i] = sproj[(size_t)b * PA + a] + tbias[a];
        vv[i] = ldin(v, a, in32);
        wc[i] = ldin(Wc, a, in32);
    }
    for (int n = 0; n < PN; ++n) {
        float cv = ldin(cov, b * PN + n, in32);
        const bf16* tr = t + (size_t)(b * PN + n) * PA;
        float s = 0.f;
#pragma unroll
        for (int i = 0; i < 4; ++i) {
            int a = tid + i * 256;
            s += vv[i] * tanhf((float)tr[a] + sp[i] + cv * wc[i]);
        }
#pragma unroll
        for (int off = 32; off; off >>= 1) s += __shfl_down(s, off);
        if ((tid & 63) == 0) red[tid >> 6] = s;
        __syncthreads();
        if (tid == 0) sc[n] = red[0] + red[1] + red[2] + red[3];
        __syncthreads();
    }
    if (tid < PN) {
        float mx = -1e30f;
        for (int n = 0; n < PN; ++n) mx = fmaxf(mx, sc[n]);
        float sum = 0.f;
        for (int n = 0; n < PN; ++n) sum += expf(sc[n] - mx);
        alpha[b * PN + tid] = expf(sc[tid] - mx) / sum;
    }
}

// out[b,h] = sum_n alpha[b,n]*gstar[b,n,h] + cbias[h]; dtype per flag
__global__ __launch_bounds__(256) void final_kernel(
    const float* __restrict__ alpha, const bf16* __restrict__ gstar,
    const float* __restrict__ cbias, const int* __restrict__ flag,
    void* __restrict__ out)
{
    int i = blockIdx.x * 256 + threadIdx.x;   // i = b*1024 + h
    int b = i >> 10, h = i & 1023;
    float s = cbias[h];
    for (int n = 0; n < PN; ++n)
        s += alpha[b * PN + n] * (float)gstar[(size_t)(b * PN + n) * PA + h];
    if (flag[0]) ((bf16*)out)[i] = (bf16)s;
    else         ((float*)out)[i] = s;
}

// ---------------------------------------------------------------------------
extern "C" void kernel_launch(void* const* d_in, const int* in_sizes, int n_in,
                              void* d_out, int out_size, void* d_ws, size_t ws_size,
                              hipStream_t stream)
{
    const void* GF  = d_in[0];
    const void* s_t = d_in[1];
    const void* cov = d_in[2];
    const void* Wg  = d_in[3];
    const void* bg  = d_in[4];
    const void* Wgs = d_in[5];
    const void* bgs = d_in[6];
    const void* Wh  = d_in[7];
    const void* Ws  = d_in[8];
    const void* Wc  = d_in[9];
    const void* v   = d_in[10];
    (void)in_sizes; (void)n_in; (void)out_size; (void)ws_size;

    // ---- workspace plan (peak ~47.5 MB) ----
    const size_t MB = 1u << 20;
    char* W = (char*)d_ws;
    bf16*  WgsT   = (bf16*) (W + 0);                    // [H,G] 8MB
    bf16*  WggsT  = (bf16*) (W + 8 * MB);               // [H,G] 8MB
    bf16*  gstar  = (bf16*) (W + 16 * MB);              // [6272,1024] 12.25MB
    bf16*  tbuf   = (bf16*) (W + (28 * MB + 512 * 1024)); // 12.25MB
    bf16*  WhT    = (bf16*) (W + 41 * MB);              // [A,H] 2MB
    bf16*  WsT    = (bf16*) (W + 43 * MB);              // [A,H] 2MB
    float* sprojP = (float*)(W + 45 * MB);              // 2MB
    float* sproj  = (float*)(W + 47 * MB);              // 0.5MB
    char*  sm     = W + (47 * MB + 512 * 1024);
    int*   flag   = (int*)  (sm);
    float* tbias  = (float*)(sm + 4 * 1024);
    float* cbias  = (float*)(sm + 8 * 1024);
    float* alpha  = (float*)(sm + 12 * 1024);           // 25KB
    float* mvpart = (float*)(sm + 40 * 1024);           // 64KB

    dim3 blk(256);

    // 0. dtype detect
    detect_kernel<<<dim3(1), blk, 0, stream>>>((const unsigned short*)GF, flag);

    // 1. WgsT = Wgs^T [H,G]
    transpose_kernel<<<dim3(PH / 64, PG / 64), blk, 0, stream>>>(Wgs, flag, WgsT, PG, PH);
    // 2. WhT = Wh^T, WsT = Ws^T [A,H]
    transpose_kernel<<<dim3(PA / 64, PH / 64), blk, 0, stream>>>(Wh, flag, WhT, PH, PA);
    transpose_kernel<<<dim3(PA / 64, PH / 64), blk, 0, stream>>>(Ws, flag, WsT, PH, PA);

    // 3. cbias = bg@Wgs + bgs  [H]
    matvec_part_kernel<<<dim3(PH / 256, 16), blk, 0, stream>>>(bg, Wgs, flag, 1, mvpart, PH, PG / 16);
    matvec_fin_kernel<<<dim3(PH / 256), blk, 0, stream>>>(mvpart, bgs, flag, cbias, 16, PH);
    // 4. tbias = cbias@Wh  [A]
    matvec_part_kernel<<<dim3(PA / 256, 16), blk, 0, stream>>>(cbias, Wh, flag, 0, mvpart, PA, PH / 16);
    matvec_fin_kernel<<<dim3(PA / 256), blk, 0, stream>>>(mvpart, nullptr, flag, tbias, 16, PA);

    // 5. WggsT[h,g] = sum_k Wgs[k,h]*Wg[g,k]: A=WgsT [H,G], Bt=Wg (raw) [G,G]
    gemm_kernel<1><<<dim3(PG / 128, PH / 128, 1), blk, 0, stream>>>(
        WgsT, Wg, flag, 0, 1, nullptr, WggsT, PH, PG, PG, PG / 64);

    // 6. gstar = GF @ Wggs: A=GF (raw) [6272,G], Bt=WggsT [H,G]
    gemm_kernel<1><<<dim3(PH / 128, PM1 / 128, 1), blk, 0, stream>>>(
        GF, WggsT, flag, 1, 0, nullptr, gstar, PM1, PH, PG, PG / 64);

    // 7. t = gstar @ Wh: A=gstar, Bt=WhT [A,H]
    gemm_kernel<1><<<dim3(PA / 128, PM1 / 128, 1), blk, 0, stream>>>(
        gstar, WhT, flag, 0, 0, nullptr, tbuf, PM1, PA, PH, PH / 64);

    // 8. sproj = s_t @ Ws: A=s_t (raw) [B,H], Bt=WsT; split-K 4
    gemm_kernel<0><<<dim3(PA / 128, 1, 4), blk, 0, stream>>>(
        s_t, WsT, flag, 1, 0, sprojP, nullptr, PB, PA, PH, (PH / 64) / 4);
    reduce4_kernel<<<dim3((PB * PA) / 256), blk, 0, stream>>>(sprojP, sproj, PB * PA);

    // 9. attention -> alpha
    attn_kernel<<<dim3(PB), blk, 0, stream>>>(tbuf, sproj, tbias, cov, Wc, v, flag, alpha);

    // 10. out = sum_n alpha*gstar + cbias
    final_kernel<<<dim3((PB * PA) / 256), blk, 0, stream>>>(alpha, gstar, cbias, flag, d_out);
}

// Round 4
// 639.650 us; speedup vs baseline: 1.3685x; 1.3685x over previous
//
#include <hip/hip_runtime.h>
#include <cstdint>
#include <cstddef>

typedef __bf16 bf16;
typedef __bf16 bf16x8 __attribute__((ext_vector_type(8)));
typedef __bf16 bf16v4 __attribute__((ext_vector_type(4)));
typedef float  f32x4  __attribute__((ext_vector_type(4)));

// Problem constants: B=128, N=49, G=4096, H=1024, A=1024  (inputs fp32 per R3)
#define PB   128
#define PN   49
#define PG   4096
#define PH   1024
#define PA   1024
#define PM1  (PB * PN)   // 6272

// ---------------------------------------------------------------------------
// dtype detect (kept from R3 — proven): flag=1 -> bf16 inputs, 0 -> fp32.
// ---------------------------------------------------------------------------
__global__ __launch_bounds__(256) void detect_kernel(
    const unsigned short* __restrict__ raw, int* __restrict__ flag)
{
    __shared__ int cnt;
    if (threadIdx.x == 0) cnt = 0;
    __syncthreads();
    unsigned short u = raw[threadIdx.x];
    float x = __uint_as_float(((unsigned int)u) << 16);
    float a = fabsf(x);
    atomicAdd(&cnt, (a >= 1e-7f && a <= 128.f) ? 1 : 0);
    __syncthreads();
    if (threadIdx.x == 0) flag[0] = (cnt >= 200) ? 1 : 0;
}

__device__ __forceinline__ float ldin(const void* p, size_t i, bool in32) {
    return in32 ? ((const float*)p)[i] : (float)((const bf16*)p)[i];
}

// raw (flag dtype) -> bf16, 8 elems/thread
__global__ __launch_bounds__(256) void cvt_kernel(
    const void* __restrict__ in, const int* __restrict__ flag,
    bf16* __restrict__ out)
{
    const bool in32 = (flag[0] == 0);
    size_t i = ((size_t)blockIdx.x * 256 + threadIdx.x) * 8;
    bf16x8 o;
    if (in32) {
        f32x4 lo = *(const f32x4*)((const float*)in + i);
        f32x4 hi = *(const f32x4*)((const float*)in + i + 4);
#pragma unroll
        for (int j = 0; j < 4; ++j) { o[j] = (bf16)lo[j]; o[4 + j] = (bf16)hi[j]; }
    } else {
        o = *(const bf16x8*)((const bf16*)in + i);
    }
    *(bf16x8*)(out + i) = o;
}

// ---------------------------------------------------------------------------
// GEMM: C[M,N] = A[M,K] @ (Bt0 [+ Bt1])^T.  128x128 tile, BK=64, 4 waves,
// mfma 16x16x32 bf16.  bf16 operands staged via global_load_lds(16B) async
// DMA (dest = wave-uniform base + lane*16 — the HW-required pattern) with a
// (chunk+row)&7 rotation: source address applies the permutation, so frag
// ds_read_b128 spreads over all 8 bank groups (R3: SQ_LDS_BANK_CONFLICT==0).
// AADAPT=1: A is a raw input (dtype per flag) staged through VGPRs instead.
// Split-K via blockIdx.z plane (fp32 Cf or bf16 Cb per BF16OUT).
// ---------------------------------------------------------------------------
template <int BF16OUT, int AADAPT, int BTERMS>
__global__ __launch_bounds__(256, 2) void gemm_kernel(
    const void* __restrict__ Araw, const bf16* __restrict__ Bt0,
    const bf16* __restrict__ Bt1, const int* __restrict__ flag,
    float* __restrict__ Cf, bf16* __restrict__ Cb,
    int M, int N, int K, int kTilesPerSplit)
{
    __shared__ __align__(16) bf16 lds[(BTERMS == 2 ? 3 : 2) * 128 * 64];
    bf16* As  = lds;
    bf16* Bs0 = lds + 128 * 64;
    bf16* Bs1 = lds + 2 * 128 * 64;

    const bool a32 = AADAPT && (flag[0] == 0);

    const int tid  = threadIdx.x;
    const int m0   = blockIdx.y * 128;
    const int n0   = blockIdx.x * 128;
    const int kt0  = blockIdx.z * kTilesPerSplit;

    const int wave = tid >> 6;
    const int lane = tid & 63;
    const int wm   = (wave >> 1) * 64;
    const int wn   = (wave & 1) * 64;
    const int lm   = lane & 15;
    const int q    = lane >> 4;

    f32x4 acc[4][4];
#pragma unroll
    for (int i = 0; i < 4; ++i)
#pragma unroll
        for (int j = 0; j < 4; ++j) acc[i][j] = (f32x4)0.0f;

    for (int kt = 0; kt < kTilesPerSplit; ++kt) {
        const int k0 = (kt0 + kt) * 64;
#pragma unroll
        for (int it = 0; it < 4; ++it) {
            int p   = it * 256 + tid;
            int row = p >> 3;
            int lc  = ((p & 7) - row) & 7;       // logical chunk held by phys slot p
            size_t offB = (size_t)(n0 + row) * K + k0 + lc * 8;
            __builtin_amdgcn_global_load_lds((void*)(Bt0 + offB), (void*)(Bs0 + p * 8), 16, 0, 0);
            if (BTERMS == 2)
                __builtin_amdgcn_global_load_lds((void*)(Bt1 + offB), (void*)(Bs1 + p * 8), 16, 0, 0);
            size_t offA = (size_t)(m0 + row) * K + k0 + lc * 8;
            if (AADAPT) {
                bf16x8 va;
                if (a32) {
                    const float* pf = (const float*)Araw + offA;
                    f32x4 lo = *(const f32x4*)pf, hi = *(const f32x4*)(pf + 4);
#pragma unroll
                    for (int j = 0; j < 4; ++j) { va[j] = (bf16)lo[j]; va[4 + j] = (bf16)hi[j]; }
                } else {
                    va = *(const bf16x8*)((const bf16*)Araw + offA);
                }
                *(bf16x8*)(As + p * 8) = va;
            } else {
                __builtin_amdgcn_global_load_lds((void*)((const bf16*)Araw + offA),
                                                 (void*)(As + p * 8), 16, 0, 0);
            }
        }
        __syncthreads();

#pragma unroll
        for (int s = 0; s < 2; ++s) {
            bf16x8 af[4], bf0[4], bf1[4];
            const int c = s * 4 + q;
#pragma unroll
            for (int mi = 0; mi < 4; ++mi) {
                int row  = wm + mi * 16 + lm;
                int slot = row * 8 + ((c + row) & 7);
                af[mi] = *(const bf16x8*)(As + slot * 8);
            }
#pragma unroll
            for (int ni = 0; ni < 4; ++ni) {
                int row  = wn + ni * 16 + lm;
                int slot = row * 8 + ((c + row) & 7);
                bf0[ni] = *(const bf16x8*)(Bs0 + slot * 8);
                if (BTERMS == 2) bf1[ni] = *(const bf16x8*)(Bs1 + slot * 8);
            }
#pragma unroll
            for (int mi = 0; mi < 4; ++mi)
#pragma unroll
                for (int ni = 0; ni < 4; ++ni) {
                    acc[mi][ni] = __builtin_amdgcn_mfma_f32_16x16x32_bf16(
                        af[mi], bf0[ni], acc[mi][ni], 0, 0, 0);
                    if (BTERMS == 2)
                        acc[mi][ni] = __builtin_amdgcn_mfma_f32_16x16x32_bf16(
                            af[mi], bf1[ni], acc[mi][ni], 0, 0, 0);
                }
        }
        __syncthreads();
    }

#pragma unroll
    for (int mi = 0; mi < 4; ++mi)
#pragma unroll
        for (int ni = 0; ni < 4; ++ni)
#pragma unroll
            for (int r = 0; r < 4; ++r) {
                int row = m0 + wm + mi * 16 + q * 4 + r;
                int col = n0 + wn + ni * 16 + lm;
                if (BF16OUT)
                    Cb[(size_t)blockIdx.z * M * N + (size_t)row * N + col] = (bf16)acc[mi][ni][r];
                else
                    Cf[(size_t)blockIdx.z * M * N + (size_t)row * N + col] = acc[mi][ni][r];
            }
}

// ---------------------------------------------------------------------------
// Transpose [R,C]->[C,R] bf16 out.  inMode 0: raw input (dtype per flag);
// inMode 1: bf16 ws buffer.  grid (C/64, R/64).
// ---------------------------------------------------------------------------
__global__ __launch_bounds__(256) void transpose_kernel(
    const void* __restrict__ in, const int* __restrict__ flag, int inMode,
    bf16* __restrict__ out, int R, int C)
{
    __shared__ bf16 tile[64][65];
    const bool in32 = (inMode == 0) && (flag[0] == 0);
    const int r0 = blockIdx.y * 64, c0 = blockIdx.x * 64;
    const int tx = threadIdx.x & 15, ty = threadIdx.x >> 4;
#pragma unroll
    for (int it = 0; it < 4; ++it) {
        int r = it * 16 + ty;
        size_t base = (size_t)(r0 + r) * C + c0 + tx * 4;
        if (in32) {
            f32x4 v = *(const f32x4*)((const float*)in + base);
#pragma unroll
            for (int i = 0; i < 4; ++i) tile[r][tx * 4 + i] = (bf16)v[i];
        } else {
            bf16v4 v = *(const bf16v4*)((const bf16*)in + base);
#pragma unroll
            for (int i = 0; i < 4; ++i) tile[r][tx * 4 + i] = v[i];
        }
    }
    __syncthreads();
#pragma unroll
    for (int it = 0; it < 4; ++it) {
        int c = it * 16 + ty;
        bf16v4 v;
#pragma unroll
        for (int i = 0; i < 4; ++i) v[i] = tile[tx * 4 + i][c];
        *(bf16v4*)(out + (size_t)(c0 + c) * R + r0 + tx * 4) = v;
    }
}

// out = plane0 + plane1, bf16 (4 elems/thread)
__global__ __launch_bounds__(256) void reduce2b_kernel(
    const float* __restrict__ parts, bf16* __restrict__ out, int n)
{
    int i = (blockIdx.x * 256 + threadIdx.x) * 4;
    f32x4 a = *(const f32x4*)(parts + i);
    f32x4 b = *(const f32x4*)(parts + n + i);
    bf16v4 o;
#pragma unroll
    for (int j = 0; j < 4; ++j) o[j] = (bf16)(a[j] + b[j]);
    *(bf16v4*)(out + i) = o;
}

// matvec (R3-proven): part[zy][c] = sum_{r in slice} x[r]*W[r,c]
__global__ __launch_bounds__(256) void matvec_part_kernel(
    const void* __restrict__ x, const void* __restrict__ W,
    const int* __restrict__ flag, int xMode,
    float* __restrict__ part, int C, int rPer)
{
    const bool in32 = (flag[0] == 0);
    int c  = blockIdx.x * 256 + threadIdx.x;
    int r0 = blockIdx.y * rPer;
    float acc = 0.f;
    for (int r = r0; r < r0 + rPer; ++r) {
        float xv = (xMode == 0) ? ((const float*)x)[r] : ldin(x, r, in32);
        acc += xv * ldin(W, (size_t)r * C + c, in32);
    }
    part[(size_t)blockIdx.y * C + c] = acc;
}

__global__ __launch_bounds__(256) void matvec_fin_kernel(
    const float* __restrict__ part, const void* __restrict__ addv,
    const int* __restrict__ flag, float* __restrict__ y, int S, int C)
{
    const bool in32 = (flag[0] == 0);
    int c = blockIdx.x * 256 + threadIdx.x;
    float acc = addv ? ldin(addv, c, in32) : 0.f;
    for (int s = 0; s < S; ++s) acc += part[(size_t)s * C + c];
    y[c] = acc;
}

// score[b,n] = v . tanh(t0+t1 + sproj0+sproj1 + tbias + cov*Wc); grid (PN,PB)
__global__ __launch_bounds__(256) void scores_kernel(
    const bf16* __restrict__ tP, const float* __restrict__ sprojP,
    const float* __restrict__ tbias, const void* __restrict__ cov,
    const void* __restrict__ Wc, const void* __restrict__ v,
    const int* __restrict__ flag, float* __restrict__ sc)
{
    const bool in32 = (flag[0] == 0);
    const int n = blockIdx.x, b = blockIdx.y, tid = threadIdx.x;
    __shared__ float red[4];
    const size_t trow = (size_t)(b * PN + n) * PA;
    const float cv = ldin(cov, b * PN + n, in32);
    float s = 0.f;
#pragma unroll
    for (int i = 0; i < 4; ++i) {
        int a = tid + i * 256;
        float tv = (float)tP[trow + a] + (float)tP[(size_t)PM1 * PA + trow + a];
        float sp = sprojP[(size_t)b * PA + a] + sprojP[(size_t)PB * PA + b * PA + a];
        s += ldin(v, a, in32) * tanhf(tv + sp + tbias[a] + cv * ldin(Wc, a, in32));
    }
#pragma unroll
    for (int off = 32; off; off >>= 1) s += __shfl_down(s, off);
    if ((tid & 63) == 0) red[tid >> 6] = s;
    __syncthreads();
    if (tid == 0) sc[b * PN + n] = red[0] + red[1] + red[2] + red[3];
}

// softmax(sc[b,:]) inline, wsum[b,g] = sum_n alpha*GFb -> hi/lo; grid (2,PB)
__global__ __launch_bounds__(256) void weighted_kernel(
    const float* __restrict__ sc, const bf16* __restrict__ GFb,
    bf16* __restrict__ whi, bf16* __restrict__ wlo)
{
    const int b = blockIdx.y;
    const int g0 = blockIdx.x * 2048 + threadIdx.x * 8;
    float e[PN];
    float mx = -1e30f;
    for (int n = 0; n < PN; ++n) mx = fmaxf(mx, sc[b * PN + n]);
    float sum = 0.f;
    for (int n = 0; n < PN; ++n) { e[n] = expf(sc[b * PN + n] - mx); sum += e[n]; }
    const float inv = 1.f / sum;
    float acc[8];
#pragma unroll
    for (int j = 0; j < 8; ++j) acc[j] = 0.f;
    for (int n = 0; n < PN; ++n) {
        float al = e[n] * inv;
        bf16x8 gv = *(const bf16x8*)(GFb + (size_t)(b * PN + n) * PG + g0);
#pragma unroll
        for (int j = 0; j < 8; ++j) acc[j] += al * (float)gv[j];
    }
    bf16x8 h, l;
#pragma unroll
    for (int j = 0; j < 8; ++j) {
        h[j] = (bf16)acc[j];
        l[j] = (bf16)(acc[j] - (float)h[j]);
    }
    *(bf16x8*)(whi + (size_t)b * PG + g0) = h;
    *(bf16x8*)(wlo + (size_t)b * PG + g0) = l;
}

// out[b,h] = sum_z cTP[z][h*PB+b] + cbias[h]; dtype per flag
__global__ __launch_bounds__(256) void final_kernel(
    const float* __restrict__ cTP, const float* __restrict__ cbias,
    const int* __restrict__ flag, void* __restrict__ out)
{
    int i = blockIdx.x * 256 + threadIdx.x;
    int b = i >> 10, h = i & 1023;
    float s = cbias[h];
#pragma unroll
    for (int z = 0; z < 8; ++z) s += cTP[(size_t)z * (PH * PB) + h * PB + b];
    if (flag[0]) ((bf16*)out)[i] = (bf16)s;
    else         ((float*)out)[i] = s;
}

// ---------------------------------------------------------------------------
extern "C" void kernel_launch(void* const* d_in, const int* in_sizes, int n_in,
                              void* d_out, int out_size, void* d_ws, size_t ws_size,
                              hipStream_t stream)
{
    const void* GF  = d_in[0];
    const void* s_t = d_in[1];
    const void* cov = d_in[2];
    const void* Wg  = d_in[3];
    const void* bg  = d_in[4];
    const void* Wgs = d_in[5];
    const void* bgs = d_in[6];
    const void* Wh  = d_in[7];
    const void* Ws  = d_in[8];
    const void* Wc  = d_in[9];
    const void* v   = d_in[10];
    (void)in_sizes; (void)n_in; (void)out_size; (void)ws_size;

    // ---- workspace plan (peak ~136 MB; lifetime-overlapped regions) ----
    const size_t MB = 1u << 20;
    char* W = (char*)d_ws;
    bf16*  GFb    = (bf16*) (W + 0);           // 51.4MB  [whole session]
    bf16*  WgsT   = (bf16*) (W + 52 * MB);     // 8.4MB   [until Wggs GEMM]
    bf16*  WhT    = (bf16*) (W + 61 * MB);     // 2MB     [until Wch GEMM]
    bf16*  WsT    = (bf16*) (W + 63 * MB);     // 2MB     [until sproj GEMM]
    bf16*  s_tb   = (bf16*) (W + 65 * MB);     // 0.25MB
    int*   flag   = (int*)  (W + 66 * MB);
    float* tbias  = (float*)(W + 66 * MB + 4096);
    float* cbias  = (float*)(W + 66 * MB + 8192);
    float* sc     = (float*)(W + 66 * MB + 12288);       // 25KB
    float* mvpart = (float*)(W + 66 * MB + 65536);       // 64KB
    bf16*  wsum_hi= (bf16*) (W + 67 * MB);     // 1MB
    bf16*  wsum_lo= (bf16*) (W + 68 * MB);     // 1MB
    float* sprojP = (float*)(W + 69 * MB);     // 1MB (2 planes)
    float* cTP    = (float*)(W + 70 * MB);     // 4MB (8 planes, c^T [H,B])
    bf16*  Wggs   = (bf16*) (W + 75 * MB);     // 8.4MB [G,H]
    bf16*  WggsT  = (bf16*) (W + 84 * MB);     // 8.4MB [H,G]
    float* WggsP  = (float*)(W + 93 * MB);     // 33.6MB fp32 (dies at reduce2b)
    bf16*  Wch    = (bf16*) (W + 93 * MB);     // 8.4MB [G,A]   (reuse, after WggsP dead)
    bf16*  WchT   = (bf16*) (W + 102 * MB);    // 8.4MB [A,G]
    bf16*  tPb    = (bf16*) (W + 111 * MB);    // 25.7MB (2 bf16 planes)

    dim3 blk(256);

    // 0. dtype detect
    detect_kernel<<<dim3(1), blk, 0, stream>>>((const unsigned short*)GF, flag);

    // 1. conversions / transposes of inputs
    cvt_kernel<<<dim3((PM1 * PG) / 2048), blk, 0, stream>>>(GF, flag, GFb);
    cvt_kernel<<<dim3((PB * PH) / 2048), blk, 0, stream>>>(s_t, flag, s_tb);
    transpose_kernel<<<dim3(PH / 64, PG / 64), blk, 0, stream>>>(Wgs, flag, 0, WgsT, PG, PH);
    transpose_kernel<<<dim3(PA / 64, PH / 64), blk, 0, stream>>>(Wh, flag, 0, WhT, PH, PA);
    transpose_kernel<<<dim3(PA / 64, PH / 64), blk, 0, stream>>>(Ws, flag, 0, WsT, PH, PA);

    // 2. cbias = bg@Wgs + bgs;  tbias = cbias@Wh
    matvec_part_kernel<<<dim3(PH / 256, 16), blk, 0, stream>>>(bg, Wgs, flag, 1, mvpart, PH, PG / 16);
    matvec_fin_kernel<<<dim3(PH / 256), blk, 0, stream>>>(mvpart, bgs, flag, cbias, 16, PH);
    matvec_part_kernel<<<dim3(PA / 256, 16), blk, 0, stream>>>(cbias, Wh, flag, 0, mvpart, PA, PH / 16);
    matvec_fin_kernel<<<dim3(PA / 256), blk, 0, stream>>>(mvpart, nullptr, flag, tbias, 16, PA);

    // 3. Wggs[G,H] = Wg @ Wgs   (A = raw Wg adaptive; split-K 2)
    gemm_kernel<0, 1, 1><<<dim3(PH / 128, PG / 128, 2), blk, 0, stream>>>(
        Wg, WgsT, nullptr, flag, WggsP, nullptr, PG, PH, PG, (PG / 64) / 2);
    reduce2b_kernel<<<dim3((PG * PH) / 1024), blk, 0, stream>>>(WggsP, Wggs, PG * PH);
    transpose_kernel<<<dim3(PH / 64, PG / 64), blk, 0, stream>>>(Wggs, flag, 1, WggsT, PG, PH);

    // 4. Wch[G,A] = Wggs @ Wh  -> transpose to WchT[A,G]
    gemm_kernel<1, 0, 1><<<dim3(PA / 128, PG / 128, 1), blk, 0, stream>>>(
        Wggs, WhT, nullptr, flag, nullptr, Wch, PG, PA, PH, PH / 64);
    transpose_kernel<<<dim3(PA / 64, PG / 64), blk, 0, stream>>>(Wch, flag, 1, WchT, PG, PA);

    // 5. t = GF @ Wch   (split-K 2, bf16 partial planes)
    gemm_kernel<1, 0, 1><<<dim3(PA / 128, PM1 / 128, 2), blk, 0, stream>>>(
        GFb, WchT, nullptr, flag, nullptr, tPb, PM1, PA, PG, (PG / 64) / 2);

    // 6. sproj = s_t @ Ws   (split-K 2, fp32 planes)
    gemm_kernel<0, 0, 1><<<dim3(PA / 128, 1, 2), blk, 0, stream>>>(
        s_tb, WsT, nullptr, flag, sprojP, nullptr, PB, PA, PH, (PH / 64) / 2);

    // 7. scores -> softmax+weighted sum (hi/lo)
    scores_kernel<<<dim3(PN, PB), blk, 0, stream>>>(tPb, sprojP, tbias, cov, Wc, v, flag, sc);
    weighted_kernel<<<dim3(PG / 2048, PB), blk, 0, stream>>>(sc, GFb, wsum_hi, wsum_lo);

    // 8. c^T[H,B] = WggsT @ wsum^T  (dual-B hi/lo, split-K 8)
    gemm_kernel<0, 0, 2><<<dim3(1, PH / 128, 8), blk, 0, stream>>>(
        WggsT, wsum_hi, wsum_lo, flag, cTP, nullptr, PH, PB, PG, (PG / 64) / 8);

    // 9. out = c + cbias
    final_kernel<<<dim3((PB * PA) / 256), blk, 0, stream>>>(cTP, cbias, flag, d_out);
}